// Round 10
// baseline (471.271 us; speedup 1.0000x reference)
//
#include <hip/hip_runtime.h>

#define LINE 64

// Wave-parallel first-fit clustering; FOUR 64-float cachelines interleaved
// per wave for ILP (R6 post-mortem: 2-way was ~2x slower than issue-count
// arithmetic -> suspected dependency-latency-bound; 4-way halves the
// per-line latency exposure).
//
// Invariant (matches reference, absmax==0.0 verified R1/R6): bases are
// created in increasing index order; extracting the first still-uncovered
// lane (s_ff1) as the next base and snapping all uncovered lanes within
// THRESH to it reproduces "first earlier base within threshold" exactly.
//
// Per line-iteration: 5 VALU + 3 SALU. Finished lines no-op (match mask 0),
// so the quad loops to max(n0..n3) with no divergence handling.
// gfx950 gotchas encoded here:
//  - v_cndmask SGPR-data + vcc violates constant-bus (R3) -> v_mov to VGPR.
//  - readlane->SGPR-read-by-VALU hazard: >=2 slots needed; the 4-way
//    interleave gives >=3 naturally (no s_nop).
//  - s_ff1 of 0 returns -1 -> readlane lane 63 -> harmless no-op.
__device__ __forceinline__ void cluster_quad(
    float x0, float x1, float x2, float x3, float thr,
    float& o0r, float& o1r, float& o2r, float& o3r) {
  float o0 = x0, o1 = x1, o2 = x2, o3 = x3;
  float d0, d1, d2, d3, vb0, vb1, vb2, vb3;
  float sb0, sb1, sb2, sb3;            // SGPR broadcasts
  unsigned long long un0, un1, un2, un3;
  int b0, b1, b2, b3;
  asm volatile(
      "s_mov_b64 %[un0], -1\n\t"
      "s_mov_b64 %[un1], -1\n\t"
      "s_mov_b64 %[un2], -1\n\t"
      "s_mov_b64 %[un3], -1\n\t"
      "s_mov_b32 %[b0], 0\n\t"
      "s_mov_b32 %[b1], 0\n\t"
      "s_mov_b32 %[b2], 0\n\t"
      "s_mov_b32 %[b3], 0\n\t"
      "1:\n\t"
      "v_readlane_b32 %[sb0], %[x0], %[b0]\n\t"
      "v_readlane_b32 %[sb1], %[x1], %[b1]\n\t"
      "v_readlane_b32 %[sb2], %[x2], %[b2]\n\t"
      "v_readlane_b32 %[sb3], %[x3], %[b3]\n\t"
      // line 0
      "v_mov_b32 %[vb0], %[sb0]\n\t"
      "v_sub_f32 %[d0], %[vb0], %[x0]\n\t"
      "v_cmp_gt_f32 vcc, %[t], abs(%[d0])\n\t"
      "s_and_b64 vcc, vcc, %[un0]\n\t"
      "v_cndmask_b32 %[o0], %[o0], %[vb0], vcc\n\t"
      "s_andn2_b64 %[un0], %[un0], vcc\n\t"
      "s_ff1_i32_b64 %[b0], %[un0]\n\t"
      // line 1
      "v_mov_b32 %[vb1], %[sb1]\n\t"
      "v_sub_f32 %[d1], %[vb1], %[x1]\n\t"
      "v_cmp_gt_f32 vcc, %[t], abs(%[d1])\n\t"
      "s_and_b64 vcc, vcc, %[un1]\n\t"
      "v_cndmask_b32 %[o1], %[o1], %[vb1], vcc\n\t"
      "s_andn2_b64 %[un1], %[un1], vcc\n\t"
      "s_ff1_i32_b64 %[b1], %[un1]\n\t"
      // line 2
      "v_mov_b32 %[vb2], %[sb2]\n\t"
      "v_sub_f32 %[d2], %[vb2], %[x2]\n\t"
      "v_cmp_gt_f32 vcc, %[t], abs(%[d2])\n\t"
      "s_and_b64 vcc, vcc, %[un2]\n\t"
      "v_cndmask_b32 %[o2], %[o2], %[vb2], vcc\n\t"
      "s_andn2_b64 %[un2], %[un2], vcc\n\t"
      "s_ff1_i32_b64 %[b2], %[un2]\n\t"
      // line 3
      "v_mov_b32 %[vb3], %[sb3]\n\t"
      "v_sub_f32 %[d3], %[vb3], %[x3]\n\t"
      "v_cmp_gt_f32 vcc, %[t], abs(%[d3])\n\t"
      "s_and_b64 vcc, vcc, %[un3]\n\t"
      "v_cndmask_b32 %[o3], %[o3], %[vb3], vcc\n\t"
      "s_andn2_b64 %[un3], %[un3], vcc\n\t"
      "s_ff1_i32_b64 %[b3], %[un3]\n\t"
      // any line still uncovered?
      "s_or_b64 vcc, %[un0], %[un1]\n\t"
      "s_or_b64 vcc, vcc, %[un2]\n\t"
      "s_or_b64 vcc, vcc, %[un3]\n\t"
      "s_cbranch_scc1 1b\n\t"
      : [o0] "+v"(o0), [o1] "+v"(o1), [o2] "+v"(o2), [o3] "+v"(o3),
        [d0] "=&v"(d0), [d1] "=&v"(d1), [d2] "=&v"(d2), [d3] "=&v"(d3),
        [vb0] "=&v"(vb0), [vb1] "=&v"(vb1), [vb2] "=&v"(vb2), [vb3] "=&v"(vb3),
        [sb0] "=&s"(sb0), [sb1] "=&s"(sb1), [sb2] "=&s"(sb2), [sb3] "=&s"(sb3),
        [un0] "=&s"(un0), [un1] "=&s"(un1), [un2] "=&s"(un2), [un3] "=&s"(un3),
        [b0] "=&s"(b0), [b1] "=&s"(b1), [b2] "=&s"(b2), [b3] "=&s"(b3)
      : [x0] "v"(x0), [x1] "v"(x1), [x2] "v"(x2), [x3] "v"(x3), [t] "s"(thr)
      : "vcc", "scc");
  o0r = o0; o1r = o1; o2r = o2; o3r = o3;
}

__global__ __launch_bounds__(256, 8) void cluster_kernel(
    const float* __restrict__ in, float* __restrict__ out,
    long long n_lines, long long total)
{
  const int lane = threadIdx.x & 63;
  const long long wid = ((long long)blockIdx.x * blockDim.x + threadIdx.x) >> 6;
  const long long n_waves = ((long long)gridDim.x * blockDim.x) >> 6;
  const long long n_quads = (n_lines + 3) >> 2;

  long long quad = wid;
  if (quad < n_quads) {
    // Lines 4q..4q+3 are contiguous: one address, immediate offsets.
    const float* p = in + quad * (4 * LINE) + lane;
    const long long l0 = 4 * quad;
    float x0 = p[0 * LINE];
    float x1 = (l0 + 1 < n_lines) ? p[1 * LINE] : x0;
    float x2 = (l0 + 2 < n_lines) ? p[2 * LINE] : x0;
    float x3 = (l0 + 3 < n_lines) ? p[3 * LINE] : x0;
    for (;;) {
      // Prefetch next quad before the data-dependent clustering loop.
      const long long nq = quad + n_waves;
      const bool has_next = nq < n_quads;
      float y0 = 0.f, y1 = 0.f, y2 = 0.f, y3 = 0.f;
      if (has_next) {
        const float* pn = in + nq * (4 * LINE) + lane;
        const long long m0 = 4 * nq;
        y0 = pn[0 * LINE];
        y1 = (m0 + 1 < n_lines) ? pn[1 * LINE] : y0;
        y2 = (m0 + 2 < n_lines) ? pn[2 * LINE] : y0;
        y3 = (m0 + 3 < n_lines) ? pn[3 * LINE] : y0;
      }

      float o0, o1, o2, o3;
      cluster_quad(x0, x1, x2, x3, 0.1f, o0, o1, o2, o3);

      float* q = out + quad * (4 * LINE) + lane;
      const long long c0 = 4 * quad;
      q[0 * LINE] = o0;
      if (c0 + 1 < n_lines) q[1 * LINE] = o1;
      if (c0 + 2 < n_lines) q[2 * LINE] = o2;
      if (c0 + 3 < n_lines) q[3 * LINE] = o3;

      if (!has_next) break;
      x0 = y0; x1 = y1; x2 = y2; x3 = y3; quad = nq;
    }
  }

  // Elements past the last full cacheline are copied unchanged (empty here).
  const long long tail = n_lines * LINE;
  for (long long i = tail + (long long)blockIdx.x * blockDim.x + threadIdx.x;
       i < total; i += (long long)gridDim.x * blockDim.x)
    out[i] = in[i];
}

extern "C" void kernel_launch(void* const* d_in, const int* in_sizes, int n_in,
                              void* d_out, int out_size, void* d_ws, size_t ws_size,
                              hipStream_t stream) {
  const float* x = (const float*)d_in[0];
  float* out = (float*)d_out;
  const long long total = (long long)in_sizes[0];
  const long long n_lines = total / LINE;

  // 2048 blocks x 256 threads = 8192 waves = full residency (256 CU x 8/SIMD);
  // each wave grid-strides over ~24 line-quads.
  const int block = 256;
  const int grid = 2048;
  cluster_kernel<<<grid, block, 0, stream>>>(x, out, n_lines, total);
}